// Round 14
// baseline (60.208 us; speedup 1.0000x reference)
//
#include <hip/hip_runtime.h>

#define NN 160      // nodes
#define BB 128      // batch
#define HH 256      // hidden
#define EE 5120     // edges
#define ST 128      // state dim
#define AC 32       // action dim

typedef __attribute__((ext_vector_type(8))) short short8;
typedef __attribute__((ext_vector_type(4))) float f32x4;
typedef unsigned short us;

__device__ inline us f2b(float f) {
    unsigned u = __builtin_bit_cast(unsigned, f);
    unsigned r = (u + 0x7FFFu + ((u >> 16) & 1u)) >> 16;
    return (us)r;
}
__device__ inline float b2f(us h) {
    return __builtin_bit_cast(float, (unsigned)h << 16);
}

// ---------- K1: graph rows + Pb/Mb (int-exact) + weight transposes + out init ----------
__global__ __launch_bounds__(256)
void k_pre(const int* __restrict__ ei, const float* __restrict__ W1,
           const float* __restrict__ W2, const float* __restrict__ state,
           const float* __restrict__ bo, us* __restrict__ Pb,
           us* __restrict__ Mb, us* __restrict__ W1t, us* __restrict__ W2t,
           float* __restrict__ out)
{
    const int bx = blockIdx.x, tid = threadIdx.x;
    if (bx < NN) {
        __shared__ int crow[NN];
        __shared__ unsigned abit[NN * NN / 32];   // 3.2 KB
        __shared__ float invdeg;
        if (tid < NN) crow[tid] = 0;
        for (int i = tid; i < NN * NN / 32; i += 256) abit[i] = 0;
        __syncthreads();
        for (int e = tid; e < EE; e += 256) {
            int s = ei[e], d = ei[EE + e];
            int p = d * NN + s;
            atomicOr(&abit[p >> 5], 1u << (p & 31));
            if (d == bx) atomicAdd(&crow[s], 1);
        }
        if (tid < NN) {
            int p = tid * NN + tid;
            atomicOr(&abit[p >> 5], 1u << (p & 31));
        }
        __syncthreads();
        if (tid == 0) {
            int dg = 0;
            for (int j = 0; j < NN; j++) dg += crow[j];
            invdeg = 1.0f / (float)(dg < 1 ? 1 : dg);
        }
        __syncthreads();
        if (tid < NN) {
            int s = 0;
            for (int k = 0; k < NN; k++) {
                int p = k * NN + tid;
                if (abit[p >> 5] & (1u << (p & 31))) s += crow[k];
            }
            Pb[bx * NN + tid] = f2b((float)s * invdeg);
            Mb[bx * NN + tid] = f2b((float)crow[tid] * invdeg);
        }
    } else if (bx < NN + 160) {                   // W1t: 256x160
        int idx = (bx - NN) * 256 + tid;
        int n = idx / NN, k = idx - n * NN;
        W1t[idx] = f2b(W1[k * HH + n]);
    } else if (bx < NN + 160 + 256) {             // W2t: 256x256
        int idx = (bx - NN - 160) * 256 + tid;
        int n = idx >> 8, k = idx & 255;
        W2t[idx] = f2b(W2[k * HH + n]);
    } else {                                      // out init: 128x128
        int idx = (bx - NN - 160 - 256) * 256 + tid;
        out[idx] = state[idx] + bo[idx & 127];
    }
}

// ---------- G1: h1t[b][h][i] = relu( sum_j W1t[h][j] * Pb[i][j]*x[b][j] + b1[h] )
// grid (2 h-half, 2 i-half, 128 b) = 512 blocks, 256 thr (4 waves over h)
__global__ __launch_bounds__(256)
void k_g1(const us* __restrict__ Pb, const float* __restrict__ state,
          const float* __restrict__ action, const us* __restrict__ W1t,
          const float* __restrict__ b1, us* __restrict__ h1t)
{
    __shared__ __align__(16) us sA[128 * 40];   // W1t-half rows (h)
    __shared__ __align__(16) us sB[80 * 40];    // Y rows (i-half)
    __shared__ float xb[NN];
    const int ho = blockIdx.x * 128, ibase = blockIdx.y * 80, b = blockIdx.z;
    const int tid = threadIdx.x, lane = tid & 63, w = tid >> 6;
    const int rl = lane & 15, kq = lane >> 4;

    if (tid < NN) xb[tid] = (tid < ST) ? state[b * ST + tid]
                                       : action[b * AC + (tid - ST)];
    __syncthreads();

    f32x4 acc[2][5];
#pragma unroll
    for (int f = 0; f < 2; f++)
#pragma unroll
        for (int j = 0; j < 5; j++) acc[f][j] = f32x4{0.f, 0.f, 0.f, 0.f};

    for (int kk = 0; kk < 5; kk++) {
        const int k0 = kk * 32;
        for (int c = tid; c < 832; c += 256) {
            if (c < 512) {                       // A: W1t-half [128][32]
                int r = c >> 2, cc = (c & 3) * 8;
                *(short8*)&sA[r * 40 + cc] =
                    *(const short8*)&W1t[(size_t)(ho + r) * NN + k0 + cc];
            } else {                             // Bt: Y on the fly [80][32]
                int q = c - 512;
                int r = q >> 2, cc = (q & 3) * 8;
                short8 p = *(const short8*)&Pb[(size_t)(ibase + r) * NN + k0 + cc];
                short8 y;
#pragma unroll
                for (int u = 0; u < 8; u++)
                    y[u] = (short)f2b(b2f((us)p[u]) * xb[k0 + cc + u]);
                *(short8*)&sB[r * 40 + cc] = y;
            }
        }
        __syncthreads();
        short8 af[2], bf[5];
#pragma unroll
        for (int f = 0; f < 2; f++)
            af[f] = *(const short8*)&sA[(w * 32 + f * 16 + rl) * 40 + kq * 8];
#pragma unroll
        for (int j = 0; j < 5; j++)
            bf[j] = *(const short8*)&sB[(j * 16 + rl) * 40 + kq * 8];
#pragma unroll
        for (int f = 0; f < 2; f++)
#pragma unroll
            for (int j = 0; j < 5; j++)
                acc[f][j] = __builtin_amdgcn_mfma_f32_16x16x32_bf16(
                    af[f], bf[j], acc[f][j], 0, 0, 0);
        __syncthreads();
    }
    // epi: D[h][i]: row h = w*32+f*16+kq*4+r, col i = j*16+rl
#pragma unroll
    for (int f = 0; f < 2; f++)
#pragma unroll
        for (int r = 0; r < 4; r++) {
            int h = ho + w * 32 + f * 16 + kq * 4 + r;
            float bias = b1[h];
#pragma unroll
            for (int j = 0; j < 5; j++) {
                int ig = ibase + j * 16 + rl;
                float v = acc[f][j][r] + bias;
                h1t[((size_t)b * HH + h) * NN + ig] = f2b(v > 0.f ? v : 0.f);
            }
        }
}

// ---------- G2: t[b][i][h] = sum_k Mb[i][k] * h1t[b][h][k]
// grid (2 h-half, 2 i-half, 128 b) = 512 blocks, 256 thr (4 waves over h)
__global__ __launch_bounds__(256)
void k_g2(const us* __restrict__ Mb, const us* __restrict__ h1t,
          us* __restrict__ t)
{
    __shared__ __align__(16) us sA[80 * 40];    // Mb i-half rows
    __shared__ __align__(16) us sB[128 * 40];   // h1t h-half rows
    const int ho = blockIdx.x * 128, ibase = blockIdx.y * 80, b = blockIdx.z;
    const int tid = threadIdx.x, lane = tid & 63, w = tid >> 6;
    const int rl = lane & 15, kq = lane >> 4;

    f32x4 acc[5][2];
#pragma unroll
    for (int f = 0; f < 5; f++)
#pragma unroll
        for (int j = 0; j < 2; j++) acc[f][j] = f32x4{0.f, 0.f, 0.f, 0.f};

    for (int kk = 0; kk < 5; kk++) {
        const int k0 = kk * 32;
        for (int c = tid; c < 832; c += 256) {
            if (c < 320) {                       // A: Mb [80][32]
                int r = c >> 2, cc = (c & 3) * 8;
                *(short8*)&sA[r * 40 + cc] =
                    *(const short8*)&Mb[(size_t)(ibase + r) * NN + k0 + cc];
            } else {                             // Bt: h1t rows [128][32]
                int q = c - 320;
                int r = q >> 2, cc = (q & 3) * 8;
                *(short8*)&sB[r * 40 + cc] =
                    *(const short8*)&h1t[((size_t)b * HH + ho + r) * NN + k0 + cc];
            }
        }
        __syncthreads();
        short8 af[5], bf[2];
#pragma unroll
        for (int f = 0; f < 5; f++)
            af[f] = *(const short8*)&sA[(f * 16 + rl) * 40 + kq * 8];
#pragma unroll
        for (int j = 0; j < 2; j++)
            bf[j] = *(const short8*)&sB[(w * 32 + j * 16 + rl) * 40 + kq * 8];
#pragma unroll
        for (int f = 0; f < 5; f++)
#pragma unroll
            for (int j = 0; j < 2; j++)
                acc[f][j] = __builtin_amdgcn_mfma_f32_16x16x32_bf16(
                    af[f], bf[j], acc[f][j], 0, 0, 0);
        __syncthreads();
    }
    // epi: D[i][h]: row i = f*16+kq*4+r, col h = w*32+j*16+rl
#pragma unroll
    for (int f = 0; f < 5; f++)
#pragma unroll
        for (int r = 0; r < 4; r++) {
            int ig = ibase + f * 16 + kq * 4 + r;
#pragma unroll
            for (int j = 0; j < 2; j++) {
                int hg = ho + w * 32 + j * 16 + rl;
                t[((size_t)b * NN + ig) * HH + hg] = f2b(acc[f][j][r]);
            }
        }
}

// ---------- G3: h2 = relu(t@W2 + b2); pool over i; head partial -> atomic out
// grid (2 h'-half, 2 i-half, 128 b) = 512 blocks, 256 thr (4 waves over h')
__global__ __launch_bounds__(256)
void k_g3(const us* __restrict__ t, const us* __restrict__ W2t,
          const float* __restrict__ b2, const float* __restrict__ Wo,
          float* __restrict__ out)
{
    __shared__ __align__(16) us sA[80 * 40];    // t i-half rows
    __shared__ __align__(16) us sB[128 * 40];   // W2t h'-half rows
    __shared__ float pp[4][128];
    __shared__ float phs[128];
    __shared__ float pts[256];
    const int ho = blockIdx.x * 128, ibase = blockIdx.y * 80, b = blockIdx.z;
    const int tid = threadIdx.x, lane = tid & 63, w = tid >> 6;
    const int rl = lane & 15, kq = lane >> 4;

    f32x4 acc[5][2];
#pragma unroll
    for (int f = 0; f < 5; f++)
#pragma unroll
        for (int j = 0; j < 2; j++) acc[f][j] = f32x4{0.f, 0.f, 0.f, 0.f};

    for (int kk = 0; kk < 8; kk++) {
        const int k0 = kk * 32;
        for (int c = tid; c < 832; c += 256) {
            if (c < 320) {                       // A: t rows [80][32]
                int r = c >> 2, cc = (c & 3) * 8;
                *(short8*)&sA[r * 40 + cc] =
                    *(const short8*)&t[((size_t)b * NN + ibase + r) * HH + k0 + cc];
            } else {                             // Bt: W2t rows [128][32]
                int q = c - 320;
                int r = q >> 2, cc = (q & 3) * 8;
                *(short8*)&sB[r * 40 + cc] =
                    *(const short8*)&W2t[(size_t)(ho + r) * HH + k0 + cc];
            }
        }
        __syncthreads();
        short8 af[5], bf[2];
#pragma unroll
        for (int f = 0; f < 5; f++)
            af[f] = *(const short8*)&sA[(f * 16 + rl) * 40 + kq * 8];
#pragma unroll
        for (int j = 0; j < 2; j++)
            bf[j] = *(const short8*)&sB[(w * 32 + j * 16 + rl) * 40 + kq * 8];
#pragma unroll
        for (int f = 0; f < 5; f++)
#pragma unroll
            for (int j = 0; j < 2; j++)
                acc[f][j] = __builtin_amdgcn_mfma_f32_16x16x32_bf16(
                    af[f], bf[j], acc[f][j], 0, 0, 0);
        __syncthreads();
    }
    // epi: bias+relu, in-lane pool over 20 i-rows (5f x 4r), slot by kq
#pragma unroll
    for (int j = 0; j < 2; j++) {
        int hl = w * 32 + j * 16 + rl;
        float bias = b2[ho + hl];
        float s = 0.f;
#pragma unroll
        for (int f = 0; f < 5; f++)
#pragma unroll
            for (int r = 0; r < 4; r++) {
                float v = acc[f][j][r] + bias;
                s += v > 0.f ? v : 0.f;
            }
        pp[kq][hl] = s;
    }
    __syncthreads();
    if (tid < 128) phs[tid] = pp[0][tid] + pp[1][tid] + pp[2][tid] + pp[3][tid];
    __syncthreads();
    // head partial over this half's 128 h' values
    {
        const int q = tid >> 7, s = tid & 127;
        float part = 0.f;
        for (int hl = q * 64; hl < q * 64 + 64; hl++)
            part += phs[hl] * Wo[(size_t)(ho + hl) * ST + s];
        pts[q * 128 + s] = part;
        __syncthreads();
        if (tid < ST)
            atomicAdd(&out[b * ST + tid], (pts[tid] + pts[128 + tid]) * (1.0f / NN));
    }
}

extern "C" void kernel_launch(void* const* d_in, const int* in_sizes, int n_in,
                              void* d_out, int out_size, void* d_ws, size_t ws_size,
                              hipStream_t stream) {
    const float* state  = (const float*)d_in[0];
    const float* action = (const float*)d_in[1];
    const int*   ei     = (const int*)d_in[2];
    const float* W1     = (const float*)d_in[3];
    const float* b1     = (const float*)d_in[4];
    const float* W2     = (const float*)d_in[5];
    const float* b2     = (const float*)d_in[6];
    const float* Wo     = (const float*)d_in[7];
    const float* bo     = (const float*)d_in[8];
    float* out = (float*)d_out;

    char* ws = (char*)d_ws;
    size_t off = 0;
    auto alloc = [&](size_t bytes) {
        void* p = ws + off;
        off += (bytes + 255) & ~(size_t)255;
        return p;
    };
    us* Pb  = (us*)alloc(NN * NN * 2);
    us* Mb  = (us*)alloc(NN * NN * 2);
    us* W1t = (us*)alloc((size_t)HH * NN * 2);
    us* W2t = (us*)alloc((size_t)HH * HH * 2);
    us* h1t = (us*)alloc((size_t)BB * HH * NN * 2);   // [b][h][i]  10.5 MB
    us* t   = (us*)alloc((size_t)BB * NN * HH * 2);   // [b][i][h]  10.5 MB

    k_pre<<<NN + 160 + 256 + 64, 256, 0, stream>>>(ei, W1, W2, state, bo,
                                                   Pb, Mb, W1t, W2t, out);
    {
        dim3 g(2, 2, BB);   // 512 blocks
        k_g1<<<g, 256, 0, stream>>>(Pb, state, action, W1t, b1, h1t);
        k_g2<<<g, 256, 0, stream>>>(Mb, h1t, t);
        k_g3<<<g, 256, 0, stream>>>(t, W2t, b2, Wo, out);
    }
}